// Round 1
// 352.032 us; speedup vs baseline: 1.0466x; 1.0466x over previous
//
#include <hip/hip_runtime.h>

#define HW 65536

typedef __attribute__((ext_vector_type(8))) short short8;   // 8 bf16 = 4 VGPRs (MFMA A/B frag)
typedef __attribute__((ext_vector_type(4))) float f32x4;    // MFMA C/D frag

static __device__ __forceinline__ unsigned short f2bf(float f) {
    unsigned int u = __float_as_uint(f);
    u += 0x7FFFu + ((u >> 16) & 1u);        // round-to-nearest-even (inputs finite)
    return (unsigned short)(u >> 16);
}
static __device__ __forceinline__ float bf2f(unsigned short s) {
    return __uint_as_float(((unsigned int)s) << 16);
}

// tanh-form gelu rewritten as h * sigmoid(2u):  gelu(h) ~= h / (1 + exp(-2*0.79788456*(h + 0.044715 h^3)))
// exp(-2u) = exp2(h*(c1 + c2*h^2)),  c1 = -2*log2(e)*0.79788456 = -2.3021178, c2 = c1*0.044715
static __device__ __forceinline__ float gelu_sig(float h) {
    float h2 = h * h;
    float z  = h * __builtin_fmaf(-0.1029392f, h2, -2.3021178f);
    float ex = __builtin_amdgcn_exp2f(z);
    return h * __builtin_amdgcn_rcpf(1.0f + ex);
}
static __device__ __forceinline__ float sigmoid_fast(float v) {
    float ex = __builtin_amdgcn_exp2f(-1.4426950f * v);
    return __builtin_amdgcn_rcpf(1.0f + ex);
}

// ---- prep: transpose weights to bf16 in workspace ----
// w1t[r][d], r = kind*64 + e (128 rows x 64): = W1[kind*64 + d][e]
// wft[o][c] (64 rows x 192):                  = Wf[c][o]
__global__ void dig_prep(const float* __restrict__ W1, const float* __restrict__ Wf,
                         unsigned short* __restrict__ w1t, unsigned short* __restrict__ wft) {
    int tid = blockIdx.x * blockDim.x + threadIdx.x;
    int stride = gridDim.x * blockDim.x;
    for (int i = tid; i < 128 * 64; i += stride) {
        int r = i >> 6, d = i & 63;
        int kind = r >> 6, e = r & 63;
        w1t[i] = f2bf(W1[(kind * 64 + d) * 64 + e]);
    }
    for (int i = tid; i < 64 * 192; i += stride) {
        int r = i / 192, c = i - r * 192;
        wft[i] = f2bf(Wf[c * 64 + r]);
    }
}

// ---- main fused kernel: 32 pixels per block, 4 waves ----
// LDS ~14.1 KB (ACC merged into XS, in-place gating) -> 6 blocks/CU at launch_bounds(256,6).
// Phase B/C split per pixel-tile so MFMA accumulator live range is 24 regs (was 48).
__global__ __launch_bounds__(256, 6) void dig_main(
    const float* __restrict__ x,     // [4][192][65536] fp32
    const float* __restrict__ W1,    // fallback path only
    const float* __restrict__ b1,    // [64]
    const float* __restrict__ W2,    // [64]
    const float* __restrict__ b2,    // [1]
    const float* __restrict__ Wf,    // fallback path only
    const float* __restrict__ bfv,   // [64]
    float* __restrict__ out,         // [4][64][65536] fp32
    const unsigned short* __restrict__ w1t_g,  // [128][64] bf16 (pre-transposed)
    const unsigned short* __restrict__ wft_g,  // [64][192] bf16 (pre-transposed)
    int wsok)
{
    __shared__ __align__(16) unsigned short XS[32 * 200];   // 12800 B: x tile [pix][c] bf16, gated in place
    __shared__ float GT[192];                               // 768 B: gate pre-acts [pair][pix]
    __shared__ float BW[132];                               // b1(0..63), W2(64..127), b2(128)

    const int tid = threadIdx.x;
    const int l   = tid & 63;
    const int w   = tid >> 6;
    const int lm  = l & 15;     // MFMA lane row/col index
    const int q   = l >> 4;     // MFMA quad

    const int tile = blockIdx.x;
    const int bb   = tile >> 11;
    const int hw0  = (tile & 2047) * 32;

    // ---------- Stage: x tile (transpose fp32[c][pix] -> bf16 XS[pix][c]) ----------
    const float* xbase = x + (size_t)bb * (192 * HW) + hw0;
    for (int idx = tid; idx < 1536; idx += 256) {          // 6 iters
        int c = idx >> 3, pg = idx & 7;
        float4 v = *(const float4*)(xbase + (size_t)c * HW + pg * 4);
        int p0 = pg * 4;
        XS[(p0 + 0) * 200 + c] = f2bf(v.x);
        XS[(p0 + 1) * 200 + c] = f2bf(v.y);
        XS[(p0 + 2) * 200 + c] = f2bf(v.z);
        XS[(p0 + 3) * 200 + c] = f2bf(v.w);
    }
    if (tid < 192)       GT[tid] = 0.f;
    if (tid < 64)        BW[tid] = b1[tid];
    else if (tid < 128)  BW[tid] = W2[tid - 64];
    else if (tid == 128) BW[128] = b2[0];
    __syncthreads();

    // ---------- A frags: wave w owns e-range [16w, 16w+16) for BOTH kinds ----------
    short8 afr[2][2];   // [kind][ks], rows = kind*64 + 16w + lm
    if (wsok) {
        #pragma unroll
        for (int kind = 0; kind < 2; ++kind)
            #pragma unroll
            for (int ks = 0; ks < 2; ++ks)
                afr[kind][ks] = *(const short8*)&w1t_g[(kind * 64 + w * 16 + lm) * 64 + ks * 32 + q * 8];
    } else {
        #pragma unroll
        for (int kind = 0; kind < 2; ++kind)
            #pragma unroll
            for (int ks = 0; ks < 2; ++ks) {
                union { short8 v; unsigned short u[8]; } tmp;
                #pragma unroll
                for (int j = 0; j < 8; ++j)
                    tmp.u[j] = f2bf(W1[(kind * 64 + ks * 32 + q * 8 + j) * 64 + (w * 16 + lm)]);
                afr[kind][ks] = tmp.v;
            }
    }

    {
        float4 b1v4 = *(const float4*)&BW[w * 16 + q * 4];
        float4 w2v4 = *(const float4*)&BW[64 + w * 16 + q * 4];
        const float b1a[4] = {b1v4.x, b1v4.y, b1v4.z, b1v4.w};
        const float w2a[4] = {w2v4.x, w2v4.y, w2v4.z, w2v4.w};

        // ---------- Phase B+C per pixel-tile: MFMA then in-register gates ----------
        #pragma unroll
        for (int pt = 0; pt < 2; ++pt) {
            f32x4 acc[2][3];   // [kind][t]; lane: e = 16w + 4q + reg, pix = pt*16 + lm
            #pragma unroll
            for (int kind = 0; kind < 2; ++kind)
                #pragma unroll
                for (int t = 0; t < 3; ++t)
                    acc[kind][t] = (f32x4){0.f, 0.f, 0.f, 0.f};

            #pragma unroll
            for (int t = 0; t < 3; ++t) {
                const unsigned short* xr = &XS[(pt * 16 + lm) * 200 + t * 64 + q * 8];
                short8 bfr0 = *(const short8*)xr;
                short8 bfr1 = *(const short8*)(xr + 32);
                #pragma unroll
                for (int kind = 0; kind < 2; ++kind) {
                    acc[kind][t] = __builtin_amdgcn_mfma_f32_16x16x32_bf16(
                        afr[kind][0], bfr0, acc[kind][t], 0, 0, 0);
                    acc[kind][t] = __builtin_amdgcn_mfma_f32_16x16x32_bf16(
                        afr[kind][1], bfr1, acc[kind][t], 0, 0, 0);
                }
            }

            // gates: reduce w2 . gelu(a_i + c_j + b1) over e (regs -> shfl over q -> LDS atomic over waves)
            #pragma unroll
            for (int i = 0; i < 3; ++i) {
                float ab[4];
                #pragma unroll
                for (int r = 0; r < 4; ++r) ab[r] = acc[0][i][r] + b1a[r];
                #pragma unroll
                for (int jj = 0; jj < 2; ++jj) {
                    const int j = (jj == 0) ? ((i == 0) ? 1 : 0) : ((i == 2) ? 1 : 2);
                    float p = 0.f;
                    #pragma unroll
                    for (int r = 0; r < 4; ++r) {
                        float h = ab[r] + acc[1][j][r];
                        p = __builtin_fmaf(w2a[r], gelu_sig(h), p);
                    }
                    p += __shfl_xor(p, 16);
                    p += __shfl_xor(p, 32);
                    if (l < 16) atomicAdd(&GT[(2 * i + jj) * 32 + pt * 16 + lm], p);
                }
            }
        }
    }
    __syncthreads();

    // ---------- Phase D (in place): XS[pix][i*64+d] = x_i + g0*x_j0 + g1*x_j1 ----------
    // Each thread's read set == its write set (3 t-slices at its own d0), so load-all-then-store is safe.
    {
        const int pix = tid >> 3;
        const int cg  = tid & 7;
        unsigned short* xrow = XS + pix * 200;

        ushort4 xv[3][2];
        #pragma unroll
        for (int t = 0; t < 3; ++t)
            #pragma unroll
            for (int ch = 0; ch < 2; ++ch)
                xv[t][ch] = *(const ushort4*)&xrow[t * 64 + cg * 4 + ch * 32];

        float fx[3][2][4];
        #pragma unroll
        for (int t = 0; t < 3; ++t)
            #pragma unroll
            for (int ch = 0; ch < 2; ++ch) {
                fx[t][ch][0] = bf2f(xv[t][ch].x);
                fx[t][ch][1] = bf2f(xv[t][ch].y);
                fx[t][ch][2] = bf2f(xv[t][ch].z);
                fx[t][ch][3] = bf2f(xv[t][ch].w);
            }

        const float b2v = BW[128];
        float g[6];
        #pragma unroll
        for (int p6 = 0; p6 < 6; ++p6)
            g[p6] = sigmoid_fast(GT[p6 * 32 + pix] + b2v);

        #pragma unroll
        for (int i = 0; i < 3; ++i) {
            const int j0c = (i == 0) ? 1 : 0;
            const int j1c = (i == 2) ? 1 : 2;
            const float g0 = g[2 * i + 0];
            const float g1 = g[2 * i + 1];
            #pragma unroll
            for (int ch = 0; ch < 2; ++ch) {
                ushort4 o;
                o.x = f2bf(__builtin_fmaf(g1, fx[j1c][ch][0], __builtin_fmaf(g0, fx[j0c][ch][0], fx[i][ch][0])));
                o.y = f2bf(__builtin_fmaf(g1, fx[j1c][ch][1], __builtin_fmaf(g0, fx[j0c][ch][1], fx[i][ch][1])));
                o.z = f2bf(__builtin_fmaf(g1, fx[j1c][ch][2], __builtin_fmaf(g0, fx[j0c][ch][2], fx[i][ch][2])));
                o.w = f2bf(__builtin_fmaf(g1, fx[j1c][ch][3], __builtin_fmaf(g0, fx[j0c][ch][3], fx[i][ch][3])));
                *(ushort4*)&xrow[i * 64 + cg * 4 + ch * 32] = o;
            }
        }
    }
    __syncthreads();

    // ---------- Phase E: out = XS(gated) @ Wf + bf via MFMA; b-frags direct from global ----------
    {
        const int mt  = w >> 1;
        const int ntb = (w & 1) * 2;
        f32x4 eacc[2];
        eacc[0] = (f32x4){0.f, 0.f, 0.f, 0.f};
        eacc[1] = (f32x4){0.f, 0.f, 0.f, 0.f};
        #pragma unroll
        for (int ks = 0; ks < 6; ++ks) {
            short8 af = *(const short8*)&XS[(mt * 16 + lm) * 200 + ks * 32 + q * 8];
            #pragma unroll
            for (int ntl = 0; ntl < 2; ++ntl) {
                short8 bw8;
                if (wsok) {
                    bw8 = *(const short8*)&wft_g[((ntb + ntl) * 16 + lm) * 192 + ks * 32 + q * 8];
                } else {
                    union { short8 v; unsigned short u[8]; } tmp;
                    #pragma unroll
                    for (int j = 0; j < 8; ++j)
                        tmp.u[j] = f2bf(Wf[(ks * 32 + q * 8 + j) * 64 + (ntb + ntl) * 16 + lm]);
                    bw8 = tmp.v;
                }
                eacc[ntl] = __builtin_amdgcn_mfma_f32_16x16x32_bf16(af, bw8, eacc[ntl], 0, 0, 0);
            }
        }
        #pragma unroll
        for (int ntl = 0; ntl < 2; ++ntl) {
            int o = (ntb + ntl) * 16 + lm;
            float bo = bfv[o];
            float* obase = out + (size_t)bb * (64 * HW) + (size_t)o * HW + hw0 + mt * 16 + q * 4;
            *(float4*)obase = make_float4(eacc[ntl][0] + bo, eacc[ntl][1] + bo,
                                          eacc[ntl][2] + bo, eacc[ntl][3] + bo);
        }
    }
}

extern "C" void kernel_launch(void* const* d_in, const int* in_sizes, int n_in,
                              void* d_out, int out_size, void* d_ws, size_t ws_size,
                              hipStream_t stream) {
    (void)in_sizes; (void)n_in; (void)out_size;
    const float* x  = (const float*)d_in[0];
    const float* W1 = (const float*)d_in[1];
    const float* b1 = (const float*)d_in[2];
    const float* W2 = (const float*)d_in[3];
    const float* b2 = (const float*)d_in[4];
    const float* Wf = (const float*)d_in[5];
    const float* bf = (const float*)d_in[6];
    float* out = (float*)d_out;

    unsigned short* w1t = (unsigned short*)d_ws;
    unsigned short* wft = w1t + 128 * 64;
    const size_t need = (size_t)(128 * 64 + 64 * 192) * sizeof(unsigned short);
    int wsok = (d_ws != nullptr && ws_size >= need) ? 1 : 0;

    if (wsok) dig_prep<<<dim3(80), dim3(256), 0, stream>>>(W1, Wf, w1t, wft);
    dig_main<<<dim3(8192), dim3(256), 0, stream>>>(x, W1, b1, W2, b2, Wf, bf, out,
                                                   w1t, wft, wsok);
}

// Round 2
// 347.667 us; speedup vs baseline: 1.0597x; 1.0126x over previous
//
#include <hip/hip_runtime.h>

#define HW 65536

typedef __attribute__((ext_vector_type(8))) short short8;   // 8 bf16 = 4 VGPRs (MFMA A/B frag)
typedef __attribute__((ext_vector_type(4))) float f32x4;    // MFMA C/D frag

static __device__ __forceinline__ unsigned short f2bf(float f) {
    unsigned int u = __float_as_uint(f);
    u += 0x7FFFu + ((u >> 16) & 1u);        // round-to-nearest-even (inputs finite)
    return (unsigned short)(u >> 16);
}
static __device__ __forceinline__ float bf2f(unsigned short s) {
    return __uint_as_float(((unsigned int)s) << 16);
}
// HW packed conversion: lo16 = bf16(a), hi16 = bf16(b), RNE — matches f2bf
static __device__ __forceinline__ unsigned int cvt_pk_bf16(float a, float b) {
    unsigned int r;
    asm("v_cvt_pk_bf16_f32 %0, %1, %2" : "=v"(r) : "v"(a), "v"(b));
    return r;
}

// tanh-form gelu as h * sigmoid(2u):  exp(-2u) = exp2(h*(c1 + c2*h^2))
static __device__ __forceinline__ float gelu_sig(float h) {
    float h2 = h * h;
    float z  = h * __builtin_fmaf(-0.1029392f, h2, -2.3021178f);
    float ex = __builtin_amdgcn_exp2f(z);
    return h * __builtin_amdgcn_rcpf(1.0f + ex);
}
static __device__ __forceinline__ float sigmoid_fast(float v) {
    float ex = __builtin_amdgcn_exp2f(-1.4426950f * v);
    return __builtin_amdgcn_rcpf(1.0f + ex);
}

// ---- prep: transpose weights to bf16 in workspace ----
__global__ void dig_prep(const float* __restrict__ W1, const float* __restrict__ Wf,
                         unsigned short* __restrict__ w1t, unsigned short* __restrict__ wft) {
    int tid = blockIdx.x * blockDim.x + threadIdx.x;
    int stride = gridDim.x * blockDim.x;
    for (int i = tid; i < 128 * 64; i += stride) {
        int r = i >> 6, d = i & 63;
        int kind = r >> 6, e = r & 63;
        w1t[i] = f2bf(W1[(kind * 64 + d) * 64 + e]);
    }
    for (int i = tid; i < 64 * 192; i += stride) {
        int r = i / 192, c = i - r * 192;
        wft[i] = f2bf(Wf[c * 64 + r]);
    }
}

// ---- main fused kernel: 64 pixels per block (2 sub-tiles of 32), 4 waves ----
// LDS = 25600 (XS) + 1536 (GT) = 27136 B -> exactly 6 blocks/CU.
// b1/W2/b2 read directly from global (L2) to stay under the LDS budget.
__global__ __launch_bounds__(256, 6) void dig_main(
    const float* __restrict__ x,     // [4][192][65536] fp32
    const float* __restrict__ W1,    // fallback path only
    const float* __restrict__ b1,    // [64]
    const float* __restrict__ W2,    // [64]
    const float* __restrict__ b2,    // [1]
    const float* __restrict__ Wf,    // fallback path only
    const float* __restrict__ bfv,   // [64]
    float* __restrict__ out,         // [4][64][65536] fp32
    const unsigned short* __restrict__ w1t_g,  // [128][64] bf16 (pre-transposed)
    const unsigned short* __restrict__ wft_g,  // [64][192] bf16 (pre-transposed)
    int wsok)
{
    __shared__ __align__(16) unsigned short XS[64 * 200];   // 25600 B: x tile [pix][c] bf16, gated in place
    __shared__ float GT[2 * 192];                           // 1536 B: gate pre-acts [subtile][pair][pix]

    const int tid = threadIdx.x;
    const int l   = tid & 63;
    const int w   = tid >> 6;
    const int lm  = l & 15;     // MFMA lane row/col index
    const int q   = l >> 4;     // MFMA quad

    const int tile = blockIdx.x;
    const int bb   = tile >> 10;
    const int hw0  = (tile & 1023) * 64;

    // ---- early small loads (L2-resident; overlap with staging) ----
    const float4 b1v4 = *(const float4*)(b1 + w * 16 + q * 4);
    const float4 w2v4 = *(const float4*)(W2 + w * 16 + q * 4);
    const float  b2v  = b2[0];

    short8 afr[2][2];   // A frags: [kind][ks], rows = kind*64 + 16w + lm
    if (wsok) {
        #pragma unroll
        for (int kind = 0; kind < 2; ++kind)
            #pragma unroll
            for (int ks = 0; ks < 2; ++ks)
                afr[kind][ks] = *(const short8*)&w1t_g[(kind * 64 + w * 16 + lm) * 64 + ks * 32 + q * 8];
    } else {
        #pragma unroll
        for (int kind = 0; kind < 2; ++kind)
            #pragma unroll
            for (int ks = 0; ks < 2; ++ks) {
                union { short8 v; unsigned short u[8]; } tmp;
                #pragma unroll
                for (int j = 0; j < 8; ++j)
                    tmp.u[j] = f2bf(W1[(kind * 64 + ks * 32 + q * 8 + j) * 64 + (w * 16 + lm)]);
                afr[kind][ks] = tmp.v;
            }
    }

    // ---------- Stage: x tile, channel-paired (fp32[c][pix] -> bf16 XS[pix][c]) ----------
    // task idx: pg = idx&15 (pixel group of 4), c2 = idx>>4 (channel pair 0..95)
    const float* xbase = x + (size_t)bb * (192 * HW) + hw0;
    #pragma unroll
    for (int it = 0; it < 6; ++it) {
        int idx = it * 256 + tid;
        int pg = idx & 15, c = (idx >> 4) * 2;
        const float* p0 = xbase + (size_t)c * HW + pg * 4;
        float4 v0 = *(const float4*)p0;
        float4 v1 = *(const float4*)(p0 + HW);
        int px = pg * 4;
        *(unsigned int*)&XS[(px + 0) * 200 + c] = cvt_pk_bf16(v0.x, v1.x);
        *(unsigned int*)&XS[(px + 1) * 200 + c] = cvt_pk_bf16(v0.y, v1.y);
        *(unsigned int*)&XS[(px + 2) * 200 + c] = cvt_pk_bf16(v0.z, v1.z);
        *(unsigned int*)&XS[(px + 3) * 200 + c] = cvt_pk_bf16(v0.w, v1.w);
    }
    if (tid < 128) { GT[tid] = 0.f; GT[tid + 128] = 0.f; GT[tid + 256] = 0.f; }
    __syncthreads();

    // ---------- Phase B+C per sub-tile / pixel-tile: MFMA then in-register gates ----------
    {
        const float b1a[4] = {b1v4.x, b1v4.y, b1v4.z, b1v4.w};
        const float w2a[4] = {w2v4.x, w2v4.y, w2v4.z, w2v4.w};

        #pragma unroll
        for (int st = 0; st < 2; ++st) {
            #pragma unroll
            for (int pt = 0; pt < 2; ++pt) {
                f32x4 acc[2][3];   // [kind][t]; lane: e = 16w + 4q + reg, pix = st*32 + pt*16 + lm
                #pragma unroll
                for (int kind = 0; kind < 2; ++kind)
                    #pragma unroll
                    for (int t = 0; t < 3; ++t)
                        acc[kind][t] = (f32x4){0.f, 0.f, 0.f, 0.f};

                #pragma unroll
                for (int t = 0; t < 3; ++t) {
                    const unsigned short* xr = &XS[(st * 32 + pt * 16 + lm) * 200 + t * 64 + q * 8];
                    short8 bfr0 = *(const short8*)xr;
                    short8 bfr1 = *(const short8*)(xr + 32);
                    #pragma unroll
                    for (int kind = 0; kind < 2; ++kind) {
                        acc[kind][t] = __builtin_amdgcn_mfma_f32_16x16x32_bf16(
                            afr[kind][0], bfr0, acc[kind][t], 0, 0, 0);
                        acc[kind][t] = __builtin_amdgcn_mfma_f32_16x16x32_bf16(
                            afr[kind][1], bfr1, acc[kind][t], 0, 0, 0);
                    }
                }

                // gates: reduce w2 . gelu(a_i + c_j + b1) over e (regs -> shfl over q -> LDS atomic over waves)
                #pragma unroll
                for (int i = 0; i < 3; ++i) {
                    float ab[4];
                    #pragma unroll
                    for (int r = 0; r < 4; ++r) ab[r] = acc[0][i][r] + b1a[r];
                    #pragma unroll
                    for (int jj = 0; jj < 2; ++jj) {
                        const int j = (jj == 0) ? ((i == 0) ? 1 : 0) : ((i == 2) ? 1 : 2);
                        float p = 0.f;
                        #pragma unroll
                        for (int r = 0; r < 4; ++r) {
                            float h = ab[r] + acc[1][j][r];
                            p = __builtin_fmaf(w2a[r], gelu_sig(h), p);
                        }
                        p += __shfl_xor(p, 16);
                        p += __shfl_xor(p, 32);
                        if (l < 16) atomicAdd(&GT[st * 192 + (2 * i + jj) * 32 + pt * 16 + lm], p);
                    }
                }
            }
        }
    }
    __syncthreads();

    // ---------- Phase D (in place): XS[pix][i*64+d] = x_i + g0*x_j0 + g1*x_j1 ----------
    // 4 threads per pixel row; each owns 4 channel-slots of 4 per t. Read set == write set.
    {
        const int pix = tid >> 2;
        const int cg  = tid & 2 ? (tid & 3) : (tid & 3);   // cg = tid & 3
        unsigned short* xrow = XS + pix * 200;

        float g[6];
        const float* gbase = &GT[(pix >> 5) * 192];
        #pragma unroll
        for (int p6 = 0; p6 < 6; ++p6)
            g[p6] = sigmoid_fast(gbase[p6 * 32 + (pix & 31)] + b2v);

        #pragma unroll
        for (int ch = 0; ch < 4; ++ch) {
            const int d0 = (tid & 3) * 4 + ch * 16;
            ushort4 xv[3];
            #pragma unroll
            for (int t = 0; t < 3; ++t)
                xv[t] = *(const ushort4*)&xrow[t * 64 + d0];
            float fx[3][4];
            #pragma unroll
            for (int t = 0; t < 3; ++t) {
                fx[t][0] = bf2f(xv[t].x); fx[t][1] = bf2f(xv[t].y);
                fx[t][2] = bf2f(xv[t].z); fx[t][3] = bf2f(xv[t].w);
            }
            #pragma unroll
            for (int i = 0; i < 3; ++i) {
                const int j0c = (i == 0) ? 1 : 0;
                const int j1c = (i == 2) ? 1 : 2;
                const float g0 = g[2 * i + 0];
                const float g1 = g[2 * i + 1];
                float o0 = __builtin_fmaf(g1, fx[j1c][0], __builtin_fmaf(g0, fx[j0c][0], fx[i][0]));
                float o1 = __builtin_fmaf(g1, fx[j1c][1], __builtin_fmaf(g0, fx[j0c][1], fx[i][1]));
                float o2 = __builtin_fmaf(g1, fx[j1c][2], __builtin_fmaf(g0, fx[j0c][2], fx[i][2]));
                float o3 = __builtin_fmaf(g1, fx[j1c][3], __builtin_fmaf(g0, fx[j0c][3], fx[i][3]));
                uint2 ov;
                ov.x = cvt_pk_bf16(o0, o1);
                ov.y = cvt_pk_bf16(o2, o3);
                *(uint2*)&xrow[i * 64 + d0] = ov;
            }
        }
        (void)cg;
    }
    __syncthreads();

    // ---------- Phase E: out = XS(gated) @ Wf + bf via MFMA; b-frags direct from global ----------
    {
        const int mt  = w >> 1;
        const int ntb = (w & 1) * 2;
        #pragma unroll
        for (int st = 0; st < 2; ++st) {
            f32x4 eacc[2];
            eacc[0] = (f32x4){0.f, 0.f, 0.f, 0.f};
            eacc[1] = (f32x4){0.f, 0.f, 0.f, 0.f};
            #pragma unroll
            for (int ks = 0; ks < 6; ++ks) {
                short8 af = *(const short8*)&XS[(st * 32 + mt * 16 + lm) * 200 + ks * 32 + q * 8];
                #pragma unroll
                for (int ntl = 0; ntl < 2; ++ntl) {
                    short8 bw8;
                    if (wsok) {
                        bw8 = *(const short8*)&wft_g[((ntb + ntl) * 16 + lm) * 192 + ks * 32 + q * 8];
                    } else {
                        union { short8 v; unsigned short u[8]; } tmp;
                        #pragma unroll
                        for (int j = 0; j < 8; ++j)
                            tmp.u[j] = f2bf(Wf[(ks * 32 + q * 8 + j) * 64 + (ntb + ntl) * 16 + lm]);
                        bw8 = tmp.v;
                    }
                    eacc[ntl] = __builtin_amdgcn_mfma_f32_16x16x32_bf16(af, bw8, eacc[ntl], 0, 0, 0);
                }
            }
            #pragma unroll
            for (int ntl = 0; ntl < 2; ++ntl) {
                int o = (ntb + ntl) * 16 + lm;
                float bo = bfv[o];
                float* obase = out + (size_t)bb * (64 * HW) + (size_t)o * HW + hw0 + st * 32 + mt * 16 + q * 4;
                *(float4*)obase = make_float4(eacc[ntl][0] + bo, eacc[ntl][1] + bo,
                                              eacc[ntl][2] + bo, eacc[ntl][3] + bo);
            }
        }
    }
}

extern "C" void kernel_launch(void* const* d_in, const int* in_sizes, int n_in,
                              void* d_out, int out_size, void* d_ws, size_t ws_size,
                              hipStream_t stream) {
    (void)in_sizes; (void)n_in; (void)out_size;
    const float* x  = (const float*)d_in[0];
    const float* W1 = (const float*)d_in[1];
    const float* b1 = (const float*)d_in[2];
    const float* W2 = (const float*)d_in[3];
    const float* b2 = (const float*)d_in[4];
    const float* Wf = (const float*)d_in[5];
    const float* bf = (const float*)d_in[6];
    float* out = (float*)d_out;

    unsigned short* w1t = (unsigned short*)d_ws;
    unsigned short* wft = w1t + 128 * 64;
    const size_t need = (size_t)(128 * 64 + 64 * 192) * sizeof(unsigned short);
    int wsok = (d_ws != nullptr && ws_size >= need) ? 1 : 0;

    if (wsok) dig_prep<<<dim3(80), dim3(256), 0, stream>>>(W1, Wf, w1t, wft);
    dig_main<<<dim3(4096), dim3(256), 0, stream>>>(x, W1, b1, W2, b2, Wf, bf, out,
                                                   w1t, wft, wsok);
}